// Round 10
// baseline (1249.830 us; speedup 1.0000x reference)
//
#include <hip/hip_runtime.h>
#include <math.h>

#define C_ 32
#define H_ 256
#define W_ 256
#define HW_ 65536
#define CHW_ 2097152          // one image's activation, floats
#define TWO_PI 6.28318530717958647692f

__device__ __forceinline__ float gelu_exact(float x) {
    return 0.5f * x * (1.0f + erff(x * 0.7071067811865475f));
}

// 256-entry LDS twiddle table tw[t] = (cos,sin)(2*pi*t/256).
__device__ __forceinline__ void build_tw(float2* tw, int tid) {
    float a = TWO_PI * (1.0f / 256.0f) * (float)tid;
    float s_, c_; sincosf(a, &s_, &c_);
    tw[tid] = make_float2(c_, s_);
}

__global__ void k_probe(float* __restrict__ out, float ws_kib) {
    if (threadIdx.x == 0 && blockIdx.x == 0) out[0] = ws_kib;
}

// ---------------------------------------------------------------------------
// K1: lift (unchanged; r7 strided-load fix retained).
// ---------------------------------------------------------------------------
__global__ __launch_bounds__(256)
void k_lift(const float* __restrict__ xb, const float* __restrict__ fc0_w,
            const float* __restrict__ fc0_b, float* __restrict__ out) {
    __shared__ float wsh[12 * 32];
    __shared__ float bsh[32];
    int tid = threadIdx.x;
    for (int n = tid; n < 384; n += 256) wsh[n] = fc0_w[n];
    if (tid < 32) bsh[tid] = fc0_b[tid];
    __syncthreads();
    int p = blockIdx.x * 256 + tid;          // b<<16 | h<<8 | w
    int w = p & 255;
    int h = (p >> 8) & 255;
    float in[12];
    const float* xp = xb + (size_t)p * 10;
    #pragma unroll
    for (int t = 0; t < 10; ++t) in[t] = xp[t];
    in[10] = (float)h * (1.0f / 255.0f);
    in[11] = (float)w * (1.0f / 255.0f);
    float* op = out + (p & 0xFFFF) + (size_t)(p >> 16) * CHW_;
    #pragma unroll
    for (int c = 0; c < 32; ++c) {
        float acc = bsh[c];
        #pragma unroll
        for (int t = 0; t < 12; ++t) acc += in[t] * wsh[t * 32 + c];
        op[(size_t)c * HW_] = acc;
    }
}

// ---------------------------------------------------------------------------
// K2: forward W-DFT (unchanged from r9: twiddle table + LDS rows).
// ---------------------------------------------------------------------------
__global__ __launch_bounds__(256)
void k_dftw(const float* __restrict__ X, float* __restrict__ S) {
    __shared__ float2 tw[256];
    __shared__ float rows[16][257];
    int tid = threadIdx.x;
    build_tw(tw, tid);
    const float* xp = X + (size_t)blockIdx.x * 4096;
    #pragma unroll
    for (int i = 0; i < 16; ++i) rows[i][tid] = xp[i * 256 + tid];
    __syncthreads();
    int r = tid >> 4, kx = tid & 15;
    const float* rp = rows[r];
    float re = 0.f, im = 0.f;
    int t = 0;
    #pragma unroll 8
    for (int w = 0; w < 256; ++w) {
        float v = rp[w];
        float2 cs = tw[t];
        re += v * cs.x;                       // e^{-iθ}: (c, -s)
        im -= v * cs.y;
        t = (t + kx) & 255;
    }
    ((float2*)S)[(size_t)blockIdx.x * 256 + tid] = make_float2(re, im);
}

// ---------------------------------------------------------------------------
// K3: forward H-DFT (unchanged from r9).
// ---------------------------------------------------------------------------
__global__ __launch_bounds__(256)
void k_dfth(const float* __restrict__ S, float* __restrict__ G) {
    __shared__ float2 tw[256];
    __shared__ float2 sl[256][16];           // 32 KB
    int tid = threadIdx.x;
    build_tw(tw, tid);
    const float2* sp = (const float2*)S + (size_t)blockIdx.x * 4096;
    #pragma unroll
    for (int i = 0; i < 16; ++i) {
        int n = i * 256 + tid;
        sl[n >> 4][n & 15] = sp[n];
    }
    __syncthreads();
    for (int o = tid; o < 512; o += 256) {
        int kyi = o >> 4, kx = o & 15;
        int ky = kyi < 16 ? kyi : (224 + kyi);
        float gr = 0.f, gi = 0.f;
        int t = 0;
        #pragma unroll 8
        for (int h = 0; h < 256; ++h) {
            float2 cs = tw[t];
            float2 v = sl[h][kx];
            gr += v.x * cs.x + v.y * cs.y;    // (x+iy)(c-is)
            gi += v.y * cs.x - v.x * cs.y;
            t = (t + ky) & 255;
        }
        ((float2*)G)[(size_t)blockIdx.x * 512 + o] = make_float2(gr, gi);
    }
}

// ---------------------------------------------------------------------------
// K4: per-(ky,kx) 32x32 complex channel mix (unchanged).
// ---------------------------------------------------------------------------
__global__ __launch_bounds__(256)
void k_mix(const float* __restrict__ G, const float* __restrict__ w1,
           const float* __restrict__ w2, float* __restrict__ G2) {
    int t = blockIdx.x * 256 + threadIdx.x;  // ((b*32+o)*32+kyi)*16+kx
    int kx  = t & 15;
    int kyi = (t >> 4) & 31;
    int o   = (t >> 9) & 31;
    int b   = t >> 14;
    const float* wp = (kyi < 16) ? w1 : w2;
    int kyj = kyi & 15;
    const float2* gp = (const float2*)G + (size_t)b * 16384 + (size_t)kyi * 16 + kx;
    float ar = 0.f, ai = 0.f;
    for (int i = 0; i < 32; ++i) {
        float2 g = gp[(size_t)i * 512];
        const float* wv = wp + ((((size_t)(i * 32 + o)) * 16 + kyj) * 16 + kx) * 2;
        ar += g.x * wv[0] - g.y * wv[1];
        ai += g.x * wv[1] + g.y * wv[0];
    }
    ((float2*)G2)[t] = make_float2(ar, ai);
}

// ---------------------------------------------------------------------------
// K5: inverse H-DFT (unchanged from r9).
// ---------------------------------------------------------------------------
__global__ __launch_bounds__(256)
void k_idfth(const float* __restrict__ G2, float* __restrict__ T) {
    __shared__ float2 tw[256];
    __shared__ float2 g[32][16];
    int tid = threadIdx.x;
    build_tw(tw, tid);
    const float2* gp = (const float2*)G2 + (size_t)blockIdx.x * 512;
    for (int n = tid; n < 512; n += 256) g[n >> 4][n & 15] = gp[n];
    __syncthreads();
    int h = tid;
    float2 acc[16];
    #pragma unroll
    for (int kx = 0; kx < 16; ++kx) acc[kx] = make_float2(0.f, 0.f);
    for (int kyi = 0; kyi < 32; ++kyi) {
        int ky = kyi < 16 ? kyi : (224 + kyi);
        float2 cs = tw[(ky * h) & 255];
        #pragma unroll
        for (int kx = 0; kx < 16; ++kx) {
            float2 v = g[kyi][kx];
            acc[kx].x += v.x * cs.x - v.y * cs.y;   // (x+iy)(c+is)
            acc[kx].y += v.x * cs.y + v.y * cs.x;
        }
    }
    float2* tp = (float2*)T + ((size_t)blockIdx.x * 256 + h) * 16;
    #pragma unroll
    for (int kx = 0; kx < 16; ++kx) {
        float sc = (kx == 0 ? 1.0f : 2.0f) * (1.0f / 65536.0f);
        tp[kx] = make_float2(acc[kx].x * sc, acc[kx].y * sc);
    }
}

// ---------------------------------------------------------------------------
// K6: inverse W-DFT + 1x1 conv + bias + GeLU + skip.
// CHANGE (r10): T-row / conv weights / bias are read DIRECTLY from global
// with block-uniform indices -> compiler scalarizes to s_load (SMEM path),
// freeing the LDS pipe (was 1536 uniform ds_read/thread). Per-lane state
// (tw, cA/sA, xv) unchanged. Same fp32 arithmetic order -> identical result.
// X and Y may alias (per-pixel read-before-write).
// ---------------------------------------------------------------------------
__global__ __launch_bounds__(256)
void k_invw_conv(const float* __restrict__ T, const float* X,
                 const float* __restrict__ cw, const float* __restrict__ cb,
                 const float* __restrict__ skip, float* Y) {
    __shared__ float2 tw[256];
    int tid = threadIdx.x;
    build_tw(tw, tid);
    int b  = blockIdx.x >> 8;
    int hh = blockIdx.x & 255;
    __syncthreads();
    int w = tid;
    float cA[16], sA[16];
    #pragma unroll
    for (int kx = 0; kx < 16; ++kx) {
        float2 cs = tw[(kx * w) & 255];
        cA[kx] = cs.x; sA[kx] = cs.y;
    }
    size_t p = (size_t)b * CHW_ + (size_t)hh * W_ + w;
    float xv[32];
    const float* xp = X + p;
    #pragma unroll
    for (int i = 0; i < 32; ++i) xv[i] = xp[(size_t)i * HW_];
    const float* sp = skip ? skip + p : nullptr;
    float* yp = Y + p;
    for (int o = 0; o < 32; ++o) {
        const float2* tp = (const float2*)T + (((size_t)(b * 32 + o)) * 256 + hh) * 16;
        float acc = cb[o];                       // uniform -> s_load
        #pragma unroll
        for (int kx = 0; kx < 16; ++kx) {
            float2 tv = tp[kx];                  // uniform -> s_load
            acc += tv.x * cA[kx] - tv.y * sA[kx];
        }
        const float* cwp = cw + o * 32;
        #pragma unroll
        for (int i = 0; i < 32; ++i) acc += xv[i] * cwp[i];   // uniform w
        float g = gelu_exact(acc);
        if (sp) g += sp[(size_t)o * HW_];
        yp[(size_t)o * HW_] = g;
    }
}

// ---------------------------------------------------------------------------
// K7: MLP head.
// CHANGE (r10): fc1_w/fc1_b/fc2_w/fc2_b read directly from global with
// uniform indices (s_load path) instead of LDS staging — the r9 profile
// showed k_mlp gated by ~4.7k uniform ds_read/thread (LDS pipe), not VALU.
// ---------------------------------------------------------------------------
__global__ __launch_bounds__(256)
void k_mlp(const float* __restrict__ X, const float* __restrict__ fc1_w,
           const float* __restrict__ fc1_b, const float* __restrict__ fc2_w,
           const float* __restrict__ fc2_b, float* __restrict__ outb) {
    int b  = blockIdx.x >> 8;
    int hh = blockIdx.x & 255;
    int w  = threadIdx.x;
    float xv[32];
    const float* xp = X + (size_t)b * CHW_ + (size_t)hh * W_ + w;
    #pragma unroll
    for (int i = 0; i < 32; ++i) xv[i] = xp[(size_t)i * HW_];
    float o5[5] = {0.f, 0.f, 0.f, 0.f, 0.f};
    #pragma unroll 4
    for (int d = 0; d < 128; ++d) {
        float a = fc1_b[d];                          // uniform -> s_load
        #pragma unroll
        for (int i = 0; i < 32; ++i) a += xv[i] * fc1_w[i * 128 + d];
        float g = gelu_exact(a);
        #pragma unroll
        for (int s = 0; s < 5; ++s) o5[s] += g * fc2_w[d * 5 + s];
    }
    float* op = outb + ((size_t)blockIdx.x * 256 + w) * 5;
    #pragma unroll
    for (int s = 0; s < 5; ++s) op[s] = o5[s] + fc2_b[s];
}

// ---------------------------------------------------------------------------
extern "C" void kernel_launch(void* const* d_in, const int* in_sizes, int n_in,
                              void* d_out, int out_size, void* d_ws, size_t ws_size,
                              hipStream_t stream) {
    const float* x      = (const float*)d_in[0];
    const float* fc0_w  = (const float*)d_in[1];
    const float* fc0_b  = (const float*)d_in[2];
    const float* w1     = (const float*)d_in[3];
    const float* w2     = (const float*)d_in[4];
    const float* conv_w = (const float*)d_in[5];
    const float* conv_b = (const float*)d_in[6];
    const float* fc1_w  = (const float*)d_in[7];
    const float* fc1_b  = (const float*)d_in[8];
    const float* fc2_w  = (const float*)d_in[9];
    const float* fc2_b  = (const float*)d_in[10];
    float* out = (float*)d_out;

    const size_t ACTb = 16777216;            // batched activation, floats
    const size_t ACTi = 2097152;             // per-image activation, floats
    const size_t STb = 2097152, Gb = 262144; // batched spectral, floats
    const size_t STi = 262144,  Gi = 32768;  // per-image spectral, floats

    if (ws_size >= 2 * ACTb * sizeof(float)) {
        // ---- BATCHED PATH (live since r7). A0,A1 in ws (128 MiB);
        // ST+G+G2 pack exactly into d_out, dead before k_mlp rewrites it.
        float* A0 = (float*)d_ws;
        float* A1 = A0 + ACTb;
        float* ST = out;
        float* G  = ST + STb;
        float* G2 = G + Gb;

        k_lift<<<2048, 256, 0, stream>>>(x, fc0_w, fc0_b, A0);
        auto layer = [&](int l, const float* Xin, float* Yout, const float* skip) {
            k_dftw<<<4096, 256, 0, stream>>>(Xin, ST);
            k_dfth<<<256, 256, 0, stream>>>(ST, G);
            k_mix<<<512, 256, 0, stream>>>(G, w1 + (size_t)l * 524288,
                                           w2 + (size_t)l * 524288, G2);
            k_idfth<<<256, 256, 0, stream>>>(G2, ST);
            k_invw_conv<<<2048, 256, 0, stream>>>(ST, Xin, conv_w + (size_t)l * 1024,
                                                  conv_b + (size_t)l * 32, skip, Yout);
        };
        layer(0, A0, A1, nullptr);   // A1 = h0
        layer(1, A0, A0, nullptr);   // in-place (per-pixel safe)
        layer(2, A0, A0, A1);        // in-place, +h0
        layer(3, A0, A1, nullptr);   // A1 = h1 (h0 dead)
        layer(4, A0, A0, nullptr);   // in-place
        layer(5, A0, A0, A1);        // in-place, +h1
        k_mlp<<<2048, 256, 0, stream>>>(A0, fc1_w, fc1_b, fc2_w, fc2_b, out);

    } else if (ws_size >= (3 * ACTi + STi + 2 * Gi) * sizeof(float)) {
        // ---- PER-IMAGE PATH (fallback; same kernels, rebased pointers).
        float* A0 = (float*)d_ws;
        float* A1 = A0 + ACTi;
        float* A2 = A1 + ACTi;
        float* ST = A2 + ACTi;
        float* G  = ST + STi;
        float* G2 = G + Gi;

        auto layer = [&](int l, const float* Xin, float* Yout, const float* skip) {
            k_dftw<<<512, 256, 0, stream>>>(Xin, ST);
            k_dfth<<<32, 256, 0, stream>>>(ST, G);
            k_mix<<<64, 256, 0, stream>>>(G, w1 + (size_t)l * 524288,
                                          w2 + (size_t)l * 524288, G2);
            k_idfth<<<32, 256, 0, stream>>>(G2, ST);
            k_invw_conv<<<256, 256, 0, stream>>>(ST, Xin, conv_w + (size_t)l * 1024,
                                                 conv_b + (size_t)l * 32, skip, Yout);
        };
        for (int b = 0; b < 8; ++b) {
            k_lift<<<256, 256, 0, stream>>>(x + (size_t)b * HW_ * 10, fc0_w, fc0_b, A0);
            layer(0, A0, A2, nullptr);   // A2 = h0
            layer(1, A0, A1, nullptr);
            layer(2, A1, A0, A2);        // +h0
            layer(3, A0, A2, nullptr);   // A2 = h1
            layer(4, A0, A1, nullptr);
            layer(5, A1, A0, A2);        // +h1
            k_mlp<<<256, 256, 0, stream>>>(A0, fc1_w, fc1_b, fc2_w, fc2_b,
                                           out + (size_t)b * 327680);
        }
    } else {
        k_probe<<<1, 64, 0, stream>>>(out, (float)(ws_size >> 10));
    }
}

// Round 11
// 1051.943 us; speedup vs baseline: 1.1881x; 1.1881x over previous
//
#include <hip/hip_runtime.h>
#include <math.h>

#define C_ 32
#define H_ 256
#define W_ 256
#define HW_ 65536
#define CHW_ 2097152          // one image's activation, floats
#define TWO_PI 6.28318530717958647692f

__device__ __forceinline__ float gelu_exact(float x) {
    return 0.5f * x * (1.0f + erff(x * 0.7071067811865475f));
}

// 256-entry LDS twiddle table tw[t] = (cos,sin)(2*pi*t/256).
__device__ __forceinline__ void build_tw(float2* tw, int tid) {
    float a = TWO_PI * (1.0f / 256.0f) * (float)tid;
    float s_, c_; sincosf(a, &s_, &c_);
    tw[tid] = make_float2(c_, s_);
}

__global__ void k_probe(float* __restrict__ out, float ws_kib) {
    if (threadIdx.x == 0 && blockIdx.x == 0) out[0] = ws_kib;
}

// ---------------------------------------------------------------------------
// K1: lift (unchanged).
// ---------------------------------------------------------------------------
__global__ __launch_bounds__(256)
void k_lift(const float* __restrict__ xb, const float* __restrict__ fc0_w,
            const float* __restrict__ fc0_b, float* __restrict__ out) {
    __shared__ float wsh[12 * 32];
    __shared__ float bsh[32];
    int tid = threadIdx.x;
    for (int n = tid; n < 384; n += 256) wsh[n] = fc0_w[n];
    if (tid < 32) bsh[tid] = fc0_b[tid];
    __syncthreads();
    int p = blockIdx.x * 256 + tid;          // b<<16 | h<<8 | w
    int w = p & 255;
    int h = (p >> 8) & 255;
    float in[12];
    const float* xp = xb + (size_t)p * 10;
    #pragma unroll
    for (int t = 0; t < 10; ++t) in[t] = xp[t];
    in[10] = (float)h * (1.0f / 255.0f);
    in[11] = (float)w * (1.0f / 255.0f);
    float* op = out + (p & 0xFFFF) + (size_t)(p >> 16) * CHW_;
    #pragma unroll
    for (int c = 0; c < 32; ++c) {
        float acc = bsh[c];
        #pragma unroll
        for (int t = 0; t < 12; ++t) acc += in[t] * wsh[t * 32 + c];
        op[(size_t)c * HW_] = acc;
    }
}

// ---------------------------------------------------------------------------
// K2: forward W-DFT. r11: 32 rows/block, 2 rows/thread — the tw[t] b64 read
// (the LDS bottleneck at r9) is amortized over two row FMAs. Per-output
// summation order unchanged. Batched grid 2048; per-image 256.
// ---------------------------------------------------------------------------
__global__ __launch_bounds__(256)
void k_dftw(const float* __restrict__ X, float* __restrict__ S) {
    __shared__ float2 tw[256];
    __shared__ float rows[32][257];          // 32.9 KB, +1 pad
    int tid = threadIdx.x;
    build_tw(tw, tid);
    const float* xp = X + (size_t)blockIdx.x * 8192;   // 32 rows
    #pragma unroll
    for (int i = 0; i < 32; ++i) rows[i][tid] = xp[i * 256 + tid];
    __syncthreads();
    int r = tid >> 4, kx = tid & 15;
    const float* rp0 = rows[r];
    const float* rp1 = rows[r + 16];
    float re0 = 0.f, im0 = 0.f, re1 = 0.f, im1 = 0.f;
    int t = 0;
    #pragma unroll 8
    for (int w = 0; w < 256; ++w) {
        float2 cs = tw[t];
        float v0 = rp0[w], v1 = rp1[w];
        re0 += v0 * cs.x; im0 -= v0 * cs.y;   // e^{-iθ}: (c, -s)
        re1 += v1 * cs.x; im1 -= v1 * cs.y;
        t = (t + kx) & 255;
    }
    size_t base = (size_t)blockIdx.x * 512;  // 32 rows × 16 kx
    ((float2*)S)[base + (size_t)r * 16 + kx]        = make_float2(re0, im0);
    ((float2*)S)[base + (size_t)(r + 16) * 16 + kx] = make_float2(re1, im1);
}

// ---------------------------------------------------------------------------
// K3: forward H-DFT. r11: thread handles the (kyi, kyi+16) pair — they share
// the sl[h][kx] read (ky0=kyi, ky1=240+kyi). 16 FLOP per 3 b64 reads.
// Batched grid 256; per-image 32.
// ---------------------------------------------------------------------------
__global__ __launch_bounds__(256)
void k_dfth(const float* __restrict__ S, float* __restrict__ G) {
    __shared__ float2 tw[256];
    __shared__ float2 sl[256][16];           // 32 KB
    int tid = threadIdx.x;
    build_tw(tw, tid);
    const float2* sp = (const float2*)S + (size_t)blockIdx.x * 4096;
    #pragma unroll
    for (int i = 0; i < 16; ++i) {
        int n = i * 256 + tid;
        sl[n >> 4][n & 15] = sp[n];
    }
    __syncthreads();
    int kyi = tid >> 4, kx = tid & 15;       // kyi in 0..15
    int ky0 = kyi;                           // rows 0..15
    int ky1 = 240 + kyi;                     // rows 240..255 (kyi+16 slot)
    float gr0 = 0.f, gi0 = 0.f, gr1 = 0.f, gi1 = 0.f;
    int t0 = 0, t1 = 0;
    #pragma unroll 8
    for (int h = 0; h < 256; ++h) {
        float2 v = sl[h][kx];
        float2 c0 = tw[t0];
        float2 c1 = tw[t1];
        gr0 += v.x * c0.x + v.y * c0.y;      // (x+iy)(c-is)
        gi0 += v.y * c0.x - v.x * c0.y;
        gr1 += v.x * c1.x + v.y * c1.y;
        gi1 += v.y * c1.x - v.x * c1.y;
        t0 = (t0 + ky0) & 255;
        t1 = (t1 + ky1) & 255;
    }
    ((float2*)G)[(size_t)blockIdx.x * 512 + kyi * 16 + kx]        = make_float2(gr0, gi0);
    ((float2*)G)[(size_t)blockIdx.x * 512 + (kyi + 16) * 16 + kx] = make_float2(gr1, gi1);
}

// ---------------------------------------------------------------------------
// K4: per-(ky,kx) 32x32 complex channel mix (unchanged).
// ---------------------------------------------------------------------------
__global__ __launch_bounds__(256)
void k_mix(const float* __restrict__ G, const float* __restrict__ w1,
           const float* __restrict__ w2, float* __restrict__ G2) {
    int t = blockIdx.x * 256 + threadIdx.x;  // ((b*32+o)*32+kyi)*16+kx
    int kx  = t & 15;
    int kyi = (t >> 4) & 31;
    int o   = (t >> 9) & 31;
    int b   = t >> 14;
    const float* wp = (kyi < 16) ? w1 : w2;
    int kyj = kyi & 15;
    const float2* gp = (const float2*)G + (size_t)b * 16384 + (size_t)kyi * 16 + kx;
    float ar = 0.f, ai = 0.f;
    for (int i = 0; i < 32; ++i) {
        float2 g = gp[(size_t)i * 512];
        const float* wv = wp + ((((size_t)(i * 32 + o)) * 16 + kyj) * 16 + kx) * 2;
        ar += g.x * wv[0] - g.y * wv[1];
        ai += g.x * wv[1] + g.y * wv[0];
    }
    ((float2*)G2)[t] = make_float2(ar, ai);
}

// ---------------------------------------------------------------------------
// K5: inverse H-DFT (unchanged — already VALU-bound).
// ---------------------------------------------------------------------------
__global__ __launch_bounds__(256)
void k_idfth(const float* __restrict__ G2, float* __restrict__ T) {
    __shared__ float2 tw[256];
    __shared__ float2 g[32][16];
    int tid = threadIdx.x;
    build_tw(tw, tid);
    const float2* gp = (const float2*)G2 + (size_t)blockIdx.x * 512;
    for (int n = tid; n < 512; n += 256) g[n >> 4][n & 15] = gp[n];
    __syncthreads();
    int h = tid;
    float2 acc[16];
    #pragma unroll
    for (int kx = 0; kx < 16; ++kx) acc[kx] = make_float2(0.f, 0.f);
    for (int kyi = 0; kyi < 32; ++kyi) {
        int ky = kyi < 16 ? kyi : (224 + kyi);
        float2 cs = tw[(ky * h) & 255];
        #pragma unroll
        for (int kx = 0; kx < 16; ++kx) {
            float2 v = g[kyi][kx];
            acc[kx].x += v.x * cs.x - v.y * cs.y;   // (x+iy)(c+is)
            acc[kx].y += v.x * cs.y + v.y * cs.x;
        }
    }
    float2* tp = (float2*)T + ((size_t)blockIdx.x * 256 + h) * 16;
    #pragma unroll
    for (int kx = 0; kx < 16; ++kx) {
        float sc = (kx == 0 ? 1.0f : 2.0f) * (1.0f / 65536.0f);
        tp[kx] = make_float2(acc[kx].x * sc, acc[kx].y * sc);
    }
}

// ---------------------------------------------------------------------------
// K6: inverse W-DFT + 1x1 conv + bias + GeLU + skip. r11 HYBRID:
//  - T rows (cold per block) staged in LDS cooperatively (r9 style);
//  - cw/cb (same 4KB for every block -> K$-hot) via scalar loads (r10 style).
// X and Y may alias (per-pixel read-before-write).
// ---------------------------------------------------------------------------
__global__ __launch_bounds__(256)
void k_invw_conv(const float* __restrict__ T, const float* X,
                 const float* __restrict__ cw, const float* __restrict__ cb,
                 const float* __restrict__ skip, float* Y) {
    __shared__ float2 tw[256];
    __shared__ float2 tsh[32][16];           // 4 KB, cold data -> LDS
    int tid = threadIdx.x;
    build_tw(tw, tid);
    int b  = blockIdx.x >> 8;
    int hh = blockIdx.x & 255;
    const float2* tp = (const float2*)T;
    for (int n = tid; n < 512; n += 256) {
        int o = n >> 4, kx = n & 15;
        tsh[o][kx] = tp[(((size_t)(b * 32 + o)) * 256 + hh) * 16 + kx];
    }
    __syncthreads();
    int w = tid;
    float cA[16], sA[16];
    #pragma unroll
    for (int kx = 0; kx < 16; ++kx) {
        float2 cs = tw[(kx * w) & 255];
        cA[kx] = cs.x; sA[kx] = cs.y;
    }
    size_t p = (size_t)b * CHW_ + (size_t)hh * W_ + w;
    float xv[32];
    const float* xp = X + p;
    #pragma unroll
    for (int i = 0; i < 32; ++i) xv[i] = xp[(size_t)i * HW_];
    const float* sp = skip ? skip + p : nullptr;
    float* yp = Y + p;
    for (int o = 0; o < 32; ++o) {
        float acc = cb[o];                   // uniform + hot -> s_load
        #pragma unroll
        for (int kx = 0; kx < 16; ++kx) {
            float2 tv = tsh[o][kx];
            acc += tv.x * cA[kx] - tv.y * sA[kx];
        }
        const float* cwp = cw + o * 32;
        #pragma unroll
        for (int i = 0; i < 32; ++i) acc += xv[i] * cwp[i];   // hot -> s_load
        float g = gelu_exact(acc);
        if (sp) g += sp[(size_t)o * HW_];
        yp[(size_t)o * HW_] = g;
    }
}

// ---------------------------------------------------------------------------
// K7: MLP head. r11: scalar weights (kept from r10) + 2 pixels/thread —
// two independent FMA chains amortize each uniform-weight fetch and double
// ILP across the s_load waits. Batched grid 1024; per-image 128.
// Pixels p0 = blk*512+tid, p1 = p0+256 (always same image: 512 | 65536).
// ---------------------------------------------------------------------------
__global__ __launch_bounds__(256)
void k_mlp(const float* __restrict__ X, const float* __restrict__ fc1_w,
           const float* __restrict__ fc1_b, const float* __restrict__ fc2_w,
           const float* __restrict__ fc2_b, float* __restrict__ outb) {
    int tid = threadIdx.x;
    int p0 = blockIdx.x * 512 + tid;         // b<<16 | hw
    int b  = p0 >> 16;
    int hw = p0 & 0xFFFF;
    const float* xp = X + (size_t)b * CHW_ + hw;
    float xv0[32], xv1[32];
    #pragma unroll
    for (int i = 0; i < 32; ++i) {
        xv0[i] = xp[(size_t)i * HW_];
        xv1[i] = xp[(size_t)i * HW_ + 256];
    }
    float o50[5] = {0.f, 0.f, 0.f, 0.f, 0.f};
    float o51[5] = {0.f, 0.f, 0.f, 0.f, 0.f};
    #pragma unroll 4
    for (int d = 0; d < 128; ++d) {
        float bd = fc1_b[d];
        float a0 = bd, a1 = bd;
        #pragma unroll
        for (int i = 0; i < 32; ++i) {
            float wv = fc1_w[i * 128 + d];
            a0 += xv0[i] * wv;
            a1 += xv1[i] * wv;
        }
        float g0 = gelu_exact(a0);
        float g1 = gelu_exact(a1);
        #pragma unroll
        for (int s = 0; s < 5; ++s) {
            float w2v = fc2_w[d * 5 + s];
            o50[s] += g0 * w2v;
            o51[s] += g1 * w2v;
        }
    }
    float* op0 = outb + (size_t)p0 * 5;
    #pragma unroll
    for (int s = 0; s < 5; ++s) op0[s] = o50[s] + fc2_b[s];
    float* op1 = outb + ((size_t)p0 + 256) * 5;
    #pragma unroll
    for (int s = 0; s < 5; ++s) op1[s] = o51[s] + fc2_b[s];
}

// ---------------------------------------------------------------------------
extern "C" void kernel_launch(void* const* d_in, const int* in_sizes, int n_in,
                              void* d_out, int out_size, void* d_ws, size_t ws_size,
                              hipStream_t stream) {
    const float* x      = (const float*)d_in[0];
    const float* fc0_w  = (const float*)d_in[1];
    const float* fc0_b  = (const float*)d_in[2];
    const float* w1     = (const float*)d_in[3];
    const float* w2     = (const float*)d_in[4];
    const float* conv_w = (const float*)d_in[5];
    const float* conv_b = (const float*)d_in[6];
    const float* fc1_w  = (const float*)d_in[7];
    const float* fc1_b  = (const float*)d_in[8];
    const float* fc2_w  = (const float*)d_in[9];
    const float* fc2_b  = (const float*)d_in[10];
    float* out = (float*)d_out;

    const size_t ACTb = 16777216;            // batched activation, floats
    const size_t ACTi = 2097152;             // per-image activation, floats
    const size_t STb = 2097152, Gb = 262144; // batched spectral, floats
    const size_t STi = 262144,  Gi = 32768;  // per-image spectral, floats

    if (ws_size >= 2 * ACTb * sizeof(float)) {
        // ---- BATCHED PATH (live since r7). A0,A1 in ws (128 MiB);
        // ST+G+G2 pack exactly into d_out, dead before k_mlp rewrites it.
        float* A0 = (float*)d_ws;
        float* A1 = A0 + ACTb;
        float* ST = out;
        float* G  = ST + STb;
        float* G2 = G + Gb;

        k_lift<<<2048, 256, 0, stream>>>(x, fc0_w, fc0_b, A0);
        auto layer = [&](int l, const float* Xin, float* Yout, const float* skip) {
            k_dftw<<<2048, 256, 0, stream>>>(Xin, ST);
            k_dfth<<<256, 256, 0, stream>>>(ST, G);
            k_mix<<<512, 256, 0, stream>>>(G, w1 + (size_t)l * 524288,
                                           w2 + (size_t)l * 524288, G2);
            k_idfth<<<256, 256, 0, stream>>>(G2, ST);
            k_invw_conv<<<2048, 256, 0, stream>>>(ST, Xin, conv_w + (size_t)l * 1024,
                                                  conv_b + (size_t)l * 32, skip, Yout);
        };
        layer(0, A0, A1, nullptr);   // A1 = h0
        layer(1, A0, A0, nullptr);   // in-place (per-pixel safe)
        layer(2, A0, A0, A1);        // in-place, +h0
        layer(3, A0, A1, nullptr);   // A1 = h1 (h0 dead)
        layer(4, A0, A0, nullptr);   // in-place
        layer(5, A0, A0, A1);        // in-place, +h1
        k_mlp<<<1024, 256, 0, stream>>>(A0, fc1_w, fc1_b, fc2_w, fc2_b, out);

    } else if (ws_size >= (3 * ACTi + STi + 2 * Gi) * sizeof(float)) {
        // ---- PER-IMAGE PATH (fallback; same kernels, rebased pointers).
        float* A0 = (float*)d_ws;
        float* A1 = A0 + ACTi;
        float* A2 = A1 + ACTi;
        float* ST = A2 + ACTi;
        float* G  = ST + STi;
        float* G2 = G + Gi;

        auto layer = [&](int l, const float* Xin, float* Yout, const float* skip) {
            k_dftw<<<256, 256, 0, stream>>>(Xin, ST);
            k_dfth<<<32, 256, 0, stream>>>(ST, G);
            k_mix<<<64, 256, 0, stream>>>(G, w1 + (size_t)l * 524288,
                                          w2 + (size_t)l * 524288, G2);
            k_idfth<<<32, 256, 0, stream>>>(G2, ST);
            k_invw_conv<<<256, 256, 0, stream>>>(ST, Xin, conv_w + (size_t)l * 1024,
                                                 conv_b + (size_t)l * 32, skip, Yout);
        };
        for (int b = 0; b < 8; ++b) {
            k_lift<<<256, 256, 0, stream>>>(x + (size_t)b * HW_ * 10, fc0_w, fc0_b, A0);
            layer(0, A0, A2, nullptr);   // A2 = h0
            layer(1, A0, A1, nullptr);
            layer(2, A1, A0, A2);        // +h0
            layer(3, A0, A2, nullptr);   // A2 = h1
            layer(4, A0, A1, nullptr);
            layer(5, A1, A0, A2);        // +h1
            k_mlp<<<128, 256, 0, stream>>>(A0, fc1_w, fc1_b, fc2_w, fc2_b,
                                           out + (size_t)b * 327680);
        }
    } else {
        k_probe<<<1, 64, 0, stream>>>(out, (float)(ws_size >> 10));
    }
}